// Round 1
// baseline (387.981 us; speedup 1.0000x reference)
//
#include <hip/hip_runtime.h>
#include <hip/hip_bf16.h>

typedef __attribute__((ext_vector_type(8))) short bf16x8;
typedef __attribute__((ext_vector_type(4))) float f32x4;

#define T_SZ 2048
#define C_SZ 1024
#define H_SZ 16
#define D_SZ 64
#define N_SZ 3072
#define M_SZ 8192

__device__ __forceinline__ unsigned short f2bf(float f) {
    unsigned int u = __float_as_uint(f);
    unsigned int r = (u + 0x7fffu + ((u >> 16) & 1u)) >> 16;
    return (unsigned short)r;
}

__device__ __forceinline__ void gload_lds16(const void* g, void* l) {
    __builtin_amdgcn_global_load_lds(
        (const __attribute__((address_space(1))) unsigned int*)g,
        (__attribute__((address_space(3))) unsigned int*)l, 16, 0, 0);
}

// ---- x fp32 -> bf16 ----
__global__ __launch_bounds__(256) void k_convert(const float* __restrict__ in,
                                                 unsigned short* __restrict__ out, int n4) {
    int i = blockIdx.x * 256 + threadIdx.x;
    if (i >= n4) return;
    float4 v = ((const float4*)in)[i];
    ushort4 u;
    u.x = f2bf(v.x); u.y = f2bf(v.y); u.z = f2bf(v.z); u.w = f2bf(v.w);
    ((ushort4*)out)[i] = u;
}

// ---- w [1024][3072] fp32 -> wt [3072][1024] bf16 ----
__global__ __launch_bounds__(256) void k_transpose(const float* __restrict__ w,
                                                   unsigned short* __restrict__ wt) {
    __shared__ float tile[32][33];
    const int nb = blockIdx.x * 32;
    const int kb = blockIdx.y * 32;
    const int tx = threadIdx.x & 31;
    const int ty = threadIdx.x >> 5;  // 0..7
#pragma unroll
    for (int i = 0; i < 32; i += 8)
        tile[ty + i][tx] = w[(size_t)(kb + ty + i) * N_SZ + nb + tx];
    __syncthreads();
#pragma unroll
    for (int i = 0; i < 32; i += 8)
        wt[(size_t)(nb + ty + i) * C_SZ + kb + tx] = f2bf(tile[tx][ty + i]);
}

// ---- QKV GEMM: A[8192][1024] bf16 @ Bt[3072][1024] bf16 -> Q/K/V [B,H,T,D] bf16 ----
__global__ __launch_bounds__(256) void k_qkv_gemm(const unsigned short* __restrict__ A,
                                                  const unsigned short* __restrict__ Bt,
                                                  unsigned short* __restrict__ Qb,
                                                  unsigned short* __restrict__ Kb,
                                                  unsigned short* __restrict__ Vb) {
    __shared__ __align__(16) unsigned short As[128 * 32];
    __shared__ __align__(16) unsigned short Bs[128 * 32];
    const int tid = threadIdx.x;
    const int lane = tid & 63, wid = tid >> 6;
    const int wm = wid & 1, wn = wid >> 1;
    const int row0 = blockIdx.x * 128;
    const int col0 = blockIdx.y * 128;
    f32x4 acc[4][4] = {};
    const int c0 = 2 * wid, c1 = 2 * wid + 1;
    const int lr = lane >> 2, lk = (lane & 3) * 8;
    const int l15 = lane & 15, lg = lane >> 4;

    for (int kt = 0; kt < 1024; kt += 32) {
        __syncthreads();
        gload_lds16(A + (size_t)(row0 + c0 * 16 + lr) * 1024 + kt + lk, As + c0 * 512);
        gload_lds16(A + (size_t)(row0 + c1 * 16 + lr) * 1024 + kt + lk, As + c1 * 512);
        gload_lds16(Bt + (size_t)(col0 + c0 * 16 + lr) * 1024 + kt + lk, Bs + c0 * 512);
        gload_lds16(Bt + (size_t)(col0 + c1 * 16 + lr) * 1024 + kt + lk, Bs + c1 * 512);
        __syncthreads();
        bf16x8 af[4], bfr[4];
#pragma unroll
        for (int m = 0; m < 4; ++m)
            af[m] = *(const bf16x8*)&As[(wm * 64 + m * 16 + l15) * 32 + lg * 8];
#pragma unroll
        for (int n = 0; n < 4; ++n)
            bfr[n] = *(const bf16x8*)&Bs[(wn * 64 + n * 16 + l15) * 32 + lg * 8];
#pragma unroll
        for (int m = 0; m < 4; ++m)
#pragma unroll
            for (int n = 0; n < 4; ++n)
                acc[m][n] = __builtin_amdgcn_mfma_f32_16x16x32_bf16(af[m], bfr[n], acc[m][n], 0, 0, 0);
    }

    const int sel = col0 >> 10;
    unsigned short* dst = (sel == 0) ? Qb : ((sel == 1) ? Kb : Vb);
#pragma unroll
    for (int m = 0; m < 4; ++m) {
#pragma unroll
        for (int n = 0; n < 4; ++n) {
            int col = col0 + wn * 64 + n * 16 + l15;
            int cc = col & 1023;
            int h = cc >> 6, d = cc & 63;
#pragma unroll
            for (int i = 0; i < 4; ++i) {
                int row = row0 + wm * 64 + m * 16 + lg * 4 + i;
                int b = row >> 11, t = row & 2047;
                size_t idx = ((size_t)(b * 16 + h) * 2048 + t) * 64 + d;
                dst[idx] = f2bf(acc[m][n][i]);
            }
        }
    }
}

// ---- causal flash attention ----
__global__ __launch_bounds__(256) void k_attn(const unsigned short* __restrict__ Qb,
                                              const unsigned short* __restrict__ Kb,
                                              const unsigned short* __restrict__ Vb,
                                              float* __restrict__ out) {
    const int qt = blockIdx.x;   // 0..31
    const int bh = blockIdx.y;   // 0..63
    const int bb = bh >> 4, hh = bh & 15;
    const unsigned short* Qp = Qb + (size_t)bh * T_SZ * D_SZ;
    const unsigned short* Kp = Kb + (size_t)bh * T_SZ * D_SZ;
    const unsigned short* Vp = Vb + (size_t)bh * T_SZ * D_SZ;
    const int tid = threadIdx.x, lane = tid & 63, wid = tid >> 6;
    const int l15 = lane & 15, lg = lane >> 4;
    const int q0 = qt * 64 + wid * 16;

    __shared__ __align__(16) unsigned short Vt[64][72];      // V^T tile: [d][key]
    __shared__ __align__(16) unsigned short Pl[4][16][72];   // per-wave P

    bf16x8 qf[2];
#pragma unroll
    for (int kh = 0; kh < 2; ++kh)
        qf[kh] = *(const bf16x8*)&Qp[(size_t)(q0 + l15) * 64 + kh * 32 + lg * 8];

    f32x4 oacc[4] = {};
    float mrow[4] = {-1e30f, -1e30f, -1e30f, -1e30f};
    float lrow[4] = {0.f, 0.f, 0.f, 0.f};
    const float scale = 0.125f;  // D^-0.5

    for (int kb = 0; kb <= qt; ++kb) {
        const int k0 = kb * 64;
        __syncthreads();
        {   // stage V^T
            const int key = tid >> 2, dc = (tid & 3) * 16;
            bf16x8 v0 = *(const bf16x8*)&Vp[(size_t)(k0 + key) * 64 + dc];
            bf16x8 v1 = *(const bf16x8*)&Vp[(size_t)(k0 + key) * 64 + dc + 8];
#pragma unroll
            for (int j = 0; j < 8; ++j) {
                Vt[dc + j][key]     = (unsigned short)v0[j];
                Vt[dc + 8 + j][key] = (unsigned short)v1[j];
            }
        }
        __syncthreads();

        // S = Q K^T
        f32x4 s[4] = {};
#pragma unroll
        for (int ct = 0; ct < 4; ++ct) {
#pragma unroll
            for (int kh = 0; kh < 2; ++kh) {
                bf16x8 kf = *(const bf16x8*)&Kp[(size_t)(k0 + ct * 16 + l15) * 64 + kh * 32 + lg * 8];
                s[ct] = __builtin_amdgcn_mfma_f32_16x16x32_bf16(qf[kh], kf, s[ct], 0, 0, 0);
            }
        }
        // scale + causal mask
        if (kb == qt) {
#pragma unroll
            for (int ct = 0; ct < 4; ++ct) {
                int key = k0 + ct * 16 + l15;
#pragma unroll
                for (int i = 0; i < 4; ++i) {
                    int qrow = q0 + lg * 4 + i;
                    s[ct][i] = (key <= qrow) ? s[ct][i] * scale : -1e30f;
                }
            }
        } else {
#pragma unroll
            for (int ct = 0; ct < 4; ++ct)
#pragma unroll
                for (int i = 0; i < 4; ++i) s[ct][i] *= scale;
        }
        // online softmax (rows live in 16-lane groups)
        float p[4][4];
#pragma unroll
        for (int i = 0; i < 4; ++i) {
            float rmax = fmaxf(fmaxf(s[0][i], s[1][i]), fmaxf(s[2][i], s[3][i]));
            rmax = fmaxf(rmax, __shfl_xor(rmax, 1));
            rmax = fmaxf(rmax, __shfl_xor(rmax, 2));
            rmax = fmaxf(rmax, __shfl_xor(rmax, 4));
            rmax = fmaxf(rmax, __shfl_xor(rmax, 8));
            float mnew = fmaxf(mrow[i], rmax);
            float sc = __expf(mrow[i] - mnew);
            float rsum = 0.f;
#pragma unroll
            for (int ct = 0; ct < 4; ++ct) {
                float pv = __expf(s[ct][i] - mnew);
                p[ct][i] = pv;
                rsum += pv;
            }
            rsum += __shfl_xor(rsum, 1);
            rsum += __shfl_xor(rsum, 2);
            rsum += __shfl_xor(rsum, 4);
            rsum += __shfl_xor(rsum, 8);
            lrow[i] = lrow[i] * sc + rsum;
            mrow[i] = mnew;
#pragma unroll
            for (int ct = 0; ct < 4; ++ct) oacc[ct][i] *= sc;
        }
        // P -> LDS (C-layout write, A-layout read)
#pragma unroll
        for (int ct = 0; ct < 4; ++ct)
#pragma unroll
            for (int i = 0; i < 4; ++i)
                Pl[wid][lg * 4 + i][ct * 16 + l15] = f2bf(p[ct][i]);
        // O += P V
#pragma unroll
        for (int ct = 0; ct < 4; ++ct) {
#pragma unroll
            for (int kh = 0; kh < 2; ++kh) {
                bf16x8 pf = *(const bf16x8*)&Pl[wid][l15][kh * 32 + lg * 8];
                bf16x8 vf = *(const bf16x8*)&Vt[ct * 16 + l15][kh * 32 + lg * 8];
                oacc[ct] = __builtin_amdgcn_mfma_f32_16x16x32_bf16(pf, vf, oacc[ct], 0, 0, 0);
            }
        }
    }
    // epilogue
#pragma unroll
    for (int ct = 0; ct < 4; ++ct) {
#pragma unroll
        for (int i = 0; i < 4; ++i) {
            int qrow = q0 + lg * 4 + i;
            float val = oacc[ct][i] / lrow[i];
            out[((size_t)bb * T_SZ + qrow) * C_SZ + hh * 64 + ct * 16 + l15] = val;
        }
    }
}

extern "C" void kernel_launch(void* const* d_in, const int* in_sizes, int n_in,
                              void* d_out, int out_size, void* d_ws, size_t ws_size,
                              hipStream_t stream) {
    const float* x = (const float*)d_in[0];
    const float* w = (const float*)d_in[1];
    float* out = (float*)d_out;
    char* ws = (char*)d_ws;
    unsigned short* xb  = (unsigned short*)(ws);
    unsigned short* wtb = (unsigned short*)(ws + 16777216);
    unsigned short* Qb  = (unsigned short*)(ws + 16777216 + 6291456);
    unsigned short* Kb  = (unsigned short*)(ws + 16777216 + 6291456 + 16777216);
    unsigned short* Vb  = (unsigned short*)(ws + 16777216 + 6291456 + 2 * 16777216);

    k_convert<<<8192, 256, 0, stream>>>(x, xb, 2097152);
    k_transpose<<<dim3(96, 32), 256, 0, stream>>>(w, wtb);
    k_qkv_gemm<<<dim3(64, 24), 256, 0, stream>>>(xb, wtb, Qb, Kb, Vb);
    k_attn<<<dim3(32, 64), 256, 0, stream>>>(Qb, Kb, Vb, out);
}